// Round 1
// 909.684 us; speedup vs baseline: 1.0068x; 1.0068x over previous
//
#include <hip/hip_runtime.h>
#include <hip/hip_bf16.h>

// ---------------------------------------------------------------------------
// Fused transformer block: LN -> MHA -> +x -> LN -> noisy-top2 MoE -> +, entropy
// Round 5:
//  - attn_k: 512-thread blocks (8 waves x 16 q-rows) -> 16 waves/CU (grid is
//    fixed at 512 blocks = 2/CU; the old 256-thread block capped us at 8
//    waves/CU and the kernel was latency-bound: MfmaUtil 23 / VALU 33 / occ 18).
//    KV tile processed in two 32-token halves so Ps shrinks to [8][2][16][40]
//    (52 KB LDS total, pitch 40 = 80B rows: 16B-aligned b128 reads, uniform
//    bank spread; <=2-way (free) b16 write conflicts).
//  - Everything else unchanged from Round 4.
// ---------------------------------------------------------------------------

#define TT   2048
#define NTOK 4096
#define CE   1024
#define DFF  4096
#define NE   8
#define CAP  1024

typedef __bf16 bf16;
typedef __attribute__((ext_vector_type(8))) bf16 bf16x8;
typedef __attribute__((ext_vector_type(4))) bf16 bf16x4;
typedef __attribute__((ext_vector_type(4))) float f32x4;

typedef __attribute__((address_space(1))) const void* as1_t;
typedef __attribute__((address_space(3))) void* as3_t;
__device__ __forceinline__ void gll16(const void* g, void* l) {
  __builtin_amdgcn_global_load_lds((as1_t)g, (as3_t)l, 16, 0, 0);
}

__device__ __forceinline__ void split2(float v, bf16& h, bf16& l) {
  h = (bf16)v;
  l = (bf16)(v - (float)h);
}

// ---------------- weight transpose + split:  W[K][N] -> WT[N][K] -----------
template <bool LO>
__global__ __launch_bounds__(256) void wsplit_k(const float* __restrict__ W,
                                                bf16* __restrict__ Th,
                                                bf16* __restrict__ Tl,
                                                int K, int N, long sW, long sT) {
  __shared__ float tile[64][65];
  const int e = blockIdx.z;
  const float* Wb = W + (long)e * sW;
  bf16* Thb = Th + (long)e * sT;
  bf16* Tlb = LO ? Tl + (long)e * sT : nullptr;
  const int k0 = blockIdx.y * 64, n0 = blockIdx.x * 64;
  const int tx = threadIdx.x & 15, ty = threadIdx.x >> 4;
#pragma unroll
  for (int i = 0; i < 4; i++) {
    int kk = ty + i * 16;
    float4 v = *(const float4*)&Wb[(long)(k0 + kk) * N + n0 + tx * 4];
    tile[kk][tx * 4 + 0] = v.x;
    tile[kk][tx * 4 + 1] = v.y;
    tile[kk][tx * 4 + 2] = v.z;
    tile[kk][tx * 4 + 3] = v.w;
  }
  __syncthreads();
#pragma unroll
  for (int i = 0; i < 4; i++) {
    int nn = ty + i * 16;
    bf16x4 hv, lv;
#pragma unroll
    for (int j = 0; j < 4; j++) {
      float v = tile[tx * 4 + j][nn];
      bf16 h, l;
      split2(v, h, l);
      hv[j] = h;
      lv[j] = l;
    }
    long o = (long)(n0 + nn) * K + k0 + tx * 4;
    *(bf16x4*)(Thb + o) = hv;
    if (LO) *(bf16x4*)(Tlb + o) = lv;
  }
}

// ---------------- V transpose+split: V[b*TT+t][vd] f32 -> VT[b][vd][t] ------
__global__ __launch_bounds__(256) void vsplit_k(const float* __restrict__ V,
                                                bf16* __restrict__ Th,
                                                bf16* __restrict__ Tl) {
  __shared__ float tile[64][65];
  const int b = blockIdx.z;
  const int vd0 = blockIdx.x * 64, t0 = blockIdx.y * 64;
  const int tx = threadIdx.x & 15, ty = threadIdx.x >> 4;
#pragma unroll
  for (int i = 0; i < 4; i++) {
    int tt = ty + i * 16;
    float4 v = *(const float4*)&V[((long)b * TT + t0 + tt) * 1024 + vd0 + tx * 4];
    tile[tt][tx * 4 + 0] = v.x;
    tile[tt][tx * 4 + 1] = v.y;
    tile[tt][tx * 4 + 2] = v.z;
    tile[tt][tx * 4 + 3] = v.w;
  }
  __syncthreads();
#pragma unroll
  for (int i = 0; i < 4; i++) {
    int vd = ty + i * 16;
    bf16x4 hv, lv;
#pragma unroll
    for (int j = 0; j < 4; j++) {
      float v = tile[tx * 4 + j][vd];
      bf16 h, l;
      split2(v, h, l);
      hv[j] = h;
      lv[j] = l;
    }
    long o = ((long)b * 1024 + vd0 + vd) * (long)TT + t0 + tx * 4;
    *(bf16x4*)(Th + o) = hv;
    *(bf16x4*)(Tl + o) = lv;
  }
}

// ------------------------------ LayerNorm ----------------------------------
__global__ __launch_bounds__(256) void ln_k(const float* __restrict__ in,
                                            const float* __restrict__ g,
                                            const float* __restrict__ b,
                                            float* __restrict__ outf,
                                            bf16* __restrict__ outh,
                                            bf16* __restrict__ outl,
                                            float* __restrict__ zp) {
  int row = blockIdx.x, tid = threadIdx.x;
  if (zp && row == 0 && tid < 64) zp[tid] = 0.f;
  const float* xr = in + (long)row * CE;
  float v[4];
  float s = 0.f, s2 = 0.f;
#pragma unroll
  for (int i = 0; i < 4; i++) {
    v[i] = xr[tid + 256 * i];
    s += v[i];
    s2 += v[i] * v[i];
  }
#pragma unroll
  for (int o = 32; o; o >>= 1) {
    s += __shfl_xor(s, o);
    s2 += __shfl_xor(s2, o);
  }
  __shared__ float rs[4], rs2[4];
  int w = tid >> 6, lane = tid & 63;
  if (lane == 0) { rs[w] = s; rs2[w] = s2; }
  __syncthreads();
  s = rs[0] + rs[1] + rs[2] + rs[3];
  s2 = rs2[0] + rs2[1] + rs2[2] + rs2[3];
  float mu = s * (1.f / CE);
  float var = s2 * (1.f / CE) - mu * mu;
  float rstd = rsqrtf(var + 1e-5f);
  long rb = (long)row * CE;
#pragma unroll
  for (int i = 0; i < 4; i++) {
    int c = tid + 256 * i;
    float y = (v[i] - mu) * rstd * g[c] + b[c];
    if (outf) outf[rb + c] = y;
    bf16 h, l;
    split2(y, h, l);
    outh[rb + c] = h;
    outl[rb + c] = l;
  }
}

// ------------------------------ Tiled GEMM ---------------------------------
// C[M,N] = A[M,K] * B^T[N,K] (bf16 pre-split). Tile TM x 128, BK=32, 4 waves.
// global_load_lds width-16 staging. NPASS=3 => hi*hi + hi*lo + lo*hi.
// EPI: 0 qkv (split Q/K bf16 + V f32), 1 resid+f32, 2 relu+bias bf16,
//      3 scatter-add gated expert output into out (atomicAdd).
template <int NPASS, int EPI, bool AGATHER, int TM>
__global__ __launch_bounds__(256, 2) void gemm_k(
    const bf16* __restrict__ Ah, const bf16* __restrict__ Al,
    const bf16* __restrict__ BTh, const bf16* __restrict__ BTl,
    void* __restrict__ O0, void* __restrict__ O1, void* __restrict__ O2,
    int M, int N, int K, const float* __restrict__ resid,
    const float* __restrict__ bias, const int* __restrict__ tokens,
    const int* __restrict__ counts, const float* __restrict__ gslot,
    long sA, long sBT, long sC, int sBias, const bf16* __restrict__ zp) {
  constexpr int NS = (NPASS > 1) ? 2 : 1;
  constexpr int MI = TM / 32;    // m-frags per wave
  constexpr int AISS = TM / 64;  // A staging issues
  __shared__ bf16 As[NS][TM * 32];   // [row][k], unpadded (global_load_lds)
  __shared__ bf16 Bs[NS][128 * 32];
  const int e = blockIdx.z;
  const int n0 = blockIdx.x * 128, m0 = blockIdx.y * TM;
  const int tid = threadIdx.x;
  const int w = tid >> 6, lane = tid & 63, lm = lane & 15, qd = lane >> 4;
  const int wm = (w & 1) * (TM / 2), wn = (w >> 1) * 64;

  const bf16* Ab = Ah + (long)e * sA;
  const bf16* AbL = (NS > 1) ? Al + (long)e * sA : nullptr;
  const bf16* Bb = BTh + (long)e * sBT;
  const bf16* BbL = (NS > 1) ? BTl + (long)e * sBT : nullptr;

  const int kc = (lane & 3) * 8;
  int cnt = 0;
  if (AGATHER || EPI == 3) cnt = counts[e];

  // A / B staging pointers (per-lane global, wave-uniform LDS base)
  const bf16* aP[AISS];
  const bf16* aPL[AISS];
  int aStep[AISS];
  int ldsA[AISS];
#pragma unroll
  for (int ii = 0; ii < AISS; ii++) {
    int sr = w * (TM / 4) + ii * 16 + (lane >> 2);
    ldsA[ii] = (w * TM + ii * 64) * 8;
    aStep[ii] = 32;
    if (AGATHER) {
      int gm = m0 + sr;
      int tk = (gm < cnt) ? tokens[e * CAP + gm] : -1;
      if (tk < 0) { aP[ii] = (const bf16*)zp + kc; aStep[ii] = 0; }
      else aP[ii] = Ab + (long)tk * K + kc;
    } else {
      aP[ii] = Ab + (long)(m0 + sr) * K + kc;
    }
    aPL[ii] = (NS > 1) ? AbL + (aP[ii] - Ab) : nullptr;
  }
  const bf16* bP[2];
  const bf16* bPL[2];
  int ldsB[2];
#pragma unroll
  for (int ii = 0; ii < 2; ii++) {
    int sr = w * 32 + ii * 16 + (lane >> 2);
    ldsB[ii] = (w * 128 + ii * 64) * 8;
    bP[ii] = Bb + (long)(n0 + sr) * K + kc;
    bPL[ii] = (NS > 1) ? BbL + (bP[ii] - Bb) : nullptr;
  }

  f32x4 acc[MI][4];
#pragma unroll
  for (int i = 0; i < MI; i++)
#pragma unroll
    for (int j = 0; j < 4; j++) acc[i][j] = (f32x4){0.f, 0.f, 0.f, 0.f};

  for (int k0 = 0; k0 < K; k0 += 32) {
#pragma unroll
    for (int ii = 0; ii < AISS; ii++) {
      gll16(aP[ii], (char*)&As[0][0] + ldsA[ii] * 2);
      if (NS > 1) gll16(aPL[ii], (char*)&As[1][0] + ldsA[ii] * 2);
      aP[ii] += aStep[ii];
      if (NS > 1) aPL[ii] += aStep[ii];
    }
#pragma unroll
    for (int ii = 0; ii < 2; ii++) {
      gll16(bP[ii], (char*)&Bs[0][0] + ldsB[ii] * 2);
      if (NS > 1) gll16(bPL[ii], (char*)&Bs[1][0] + ldsB[ii] * 2);
      bP[ii] += 32;
      if (NS > 1) bPL[ii] += 32;
    }
    __syncthreads();
    bf16x8 af[NS][MI], bfv[NS][4];
#pragma unroll
    for (int j = 0; j < 4; j++)
#pragma unroll
      for (int s = 0; s < NS; s++)
        bfv[s][j] = *(const bf16x8*)&Bs[s][(wn + j * 16 + lm) * 32 + qd * 8];
#pragma unroll
    for (int i = 0; i < MI; i++)
#pragma unroll
      for (int s = 0; s < NS; s++)
        af[s][i] = *(const bf16x8*)&As[s][(wm + i * 16 + lm) * 32 + qd * 8];
#pragma unroll
    for (int i = 0; i < MI; i++)
#pragma unroll
      for (int j = 0; j < 4; j++) {
        acc[i][j] = __builtin_amdgcn_mfma_f32_16x16x32_bf16(
            af[0][i], bfv[0][j], acc[i][j], 0, 0, 0);
        if (NPASS > 1) {
          acc[i][j] = __builtin_amdgcn_mfma_f32_16x16x32_bf16(
              af[0][i], bfv[1][j], acc[i][j], 0, 0, 0);
          acc[i][j] = __builtin_amdgcn_mfma_f32_16x16x32_bf16(
              af[1][i], bfv[0][j], acc[i][j], 0, 0, 0);
        }
      }
    __syncthreads();
  }
  // ---- epilogue: C/D layout col=lane&15, row=quad*4+reg ----
#pragma unroll
  for (int i = 0; i < MI; i++)
#pragma unroll
    for (int j = 0; j < 4; j++) {
      long row = m0 + wm + i * 16 + qd * 4;  // +r
      long col = n0 + wn + j * 16 + lm;
      if (EPI == 0) {
        if (col < 2048) {  // Q,K: split stores
          bf16* qh = (bf16*)O0;
          bf16* ql = (bf16*)O1;
#pragma unroll
          for (int r = 0; r < 4; r++) {
            bf16 h, l;
            split2(acc[i][j][r], h, l);
            qh[(row + r) * 2048 + col] = h;
            ql[(row + r) * 2048 + col] = l;
          }
        } else {  // V: coalesced f32 rows -> vtmp[row][vd]
          float* vt = (float*)O2;
          long vd = col - 2048;
#pragma unroll
          for (int r = 0; r < 4; r++) vt[(row + r) * 1024 + vd] = acc[i][j][r];
        }
      } else if (EPI == 1) {
        float* outp = (float*)O0;
#pragma unroll
        for (int r = 0; r < 4; r++)
          outp[(row + r) * N + col] = resid[(row + r) * N + col] + acc[i][j][r];
      } else if (EPI == 2) {
        bf16* hid = (bf16*)O0;
        float bv = bias[e * sBias + col];
#pragma unroll
        for (int r = 0; r < 4; r++) {
          float t = acc[i][j][r] + bv;
          hid[(long)e * sC + (row + r) * (long)N + col] =
              (bf16)(t > 0.f ? t : 0.f);
        }
      } else {  // EPI==3: out[tok] += gate * (acc + b2)
        float* outp = (float*)O0;
        float bv = bias[e * sBias + col];
#pragma unroll
        for (int r = 0; r < 4; r++) {
          long rr = row + r;
          if (rr < cnt) {
            int tok = tokens[e * CAP + rr];
            float gv = gslot[e * CAP + rr];
            atomicAdd(&outp[(long)tok * CE + col], gv * (acc[i][j][r] + bv));
          }
        }
      }
    }
}

// ------------------------------ Flash attention ----------------------------
// 128 q-rows/block as 8 waves x 16 rows (512 thr). Grid is fixed at 512
// blocks = 2 blocks/CU, so waves/CU = 16 (was 8 with 4-wave blocks): the
// kernel is latency-bound (MfmaUtil 23/VALU 33/occ 18), more resident waves
// is the lever. KV tile (64 tok) processed in two 32-token halves: scores ->
// p/split -> Ps(half) -> PV(kcl=half); Ps shrinks to [8][2][16][40]
// (pitch 40 = 80B rows: 16B-aligned b128 reads, uniform banks; b16 writes
// <=2-way). LDS 52KB/block -> 104KB/CU at 2 blocks. No-max base-2 softmax
// unchanged: p = exp2(s*SC), per-lane l, reduced once at the end.
__global__ __launch_bounds__(512, 4) void attn_k(
    const bf16* __restrict__ qkvh, const bf16* __restrict__ qkvl,
    const bf16* __restrict__ VTh, const bf16* __restrict__ VTl,
    bf16* __restrict__ attn_h, bf16* __restrict__ attn_l) {
  const int qt = blockIdx.x, h = blockIdx.y, b = blockIdx.z;
  const int tid = threadIdx.x, w = tid >> 6, lane = tid & 63;
  const int lm = lane & 15, qd = lane >> 4;
  __shared__ bf16 Ks[2][64 * 64];
  __shared__ bf16 Vs[2][64 * 64];
  __shared__ bf16 Ps[8][2][16][40];
  const long bb = (long)b * TT;

  // Q fragments: 16 rows per wave, rows w*16+lm
  bf16x8 qfh[2], qfl[2];
  {
    long qrow = (bb + qt * 128 + w * 16 + lm) * 2048 + h * 64;
#pragma unroll
    for (int kk = 0; kk < 2; kk++) {
      qfh[kk] = *(const bf16x8*)(qkvh + qrow + kk * 32 + qd * 8);
      qfl[kk] = *(const bf16x8*)(qkvl + qrow + kk * 32 + qd * 8);
    }
  }

  // staging: 512 threads cover the full 64x64 tile in one slice each
  const int ktok = tid >> 3, dc = tid & 7;  // ktok 0..63
  const int kws = ktok * 64 + ((dc ^ (ktok & 7)) * 8);
  const long gK0 = (bb + ktok) * 2048 + 1024 + h * 64 + dc * 8;
  const int vd = tid >> 3, tc = tid & 7;    // vd 0..63
  const int vws = vd * 64 + ((tc ^ (vd & 7)) * 8);
  const long gV0 = ((long)b * 1024 + h * 64 + vd) * (long)TT + tc * 8;

  const bf16* pKh = qkvh + gK0;
  const bf16* pKl = qkvl + gK0;
  const bf16* pVh = VTh + gV0;
  const bf16* pVl = VTl + gV0;

  float4 rkh, rkl, rvh, rvl;
#define LOADT()                  \
  do {                           \
    rkh = *(const float4*)(pKh); \
    rkl = *(const float4*)(pKl); \
    rvh = *(const float4*)(pVh); \
    rvl = *(const float4*)(pVl); \
  } while (0)
  LOADT();

  float l_lane[4];
  f32x4 o[4];
#pragma unroll
  for (int r = 0; r < 4; r++) l_lane[r] = 0.f;
#pragma unroll
  for (int nt = 0; nt < 4; nt++) o[nt] = (f32x4){0.f, 0.f, 0.f, 0.f};

  const float SC = 0.125f * 1.4426950408889634f;  // 1/sqrt(64) * log2(e)

  for (int kt = 0; kt < TT / 64; kt++) {
    __syncthreads();
    *(float4*)&Ks[0][kws] = rkh;
    *(float4*)&Ks[1][kws] = rkl;
    *(float4*)&Vs[0][vws] = rvh;
    *(float4*)&Vs[1][vws] = rvl;
    if (kt != TT / 64 - 1) {
      pKh += 64 * 2048; pKl += 64 * 2048; pVh += 64; pVl += 64;
      LOADT();
    }
    __syncthreads();
#pragma unroll
    for (int th = 0; th < 2; th++) {
      // scores for token half th (tokens th*32 .. th*32+31)
      f32x4 sv[2];
#pragma unroll
      for (int ntl = 0; ntl < 2; ntl++) sv[ntl] = (f32x4){0.f, 0.f, 0.f, 0.f};
#pragma unroll
      for (int ntl = 0; ntl < 2; ntl++) {
        int tok = (th * 2 + ntl) * 16 + lm;
#pragma unroll
        for (int kk = 0; kk < 2; kk++) {
          int slot = ((kk * 4 + qd) ^ (lm & 7)) * 8;
          bf16x8 kh = *(const bf16x8*)&Ks[0][tok * 64 + slot];
          bf16x8 kl = *(const bf16x8*)&Ks[1][tok * 64 + slot];
          sv[ntl] = __builtin_amdgcn_mfma_f32_16x16x32_bf16(qfh[kk], kh,
                                                            sv[ntl], 0, 0, 0);
          sv[ntl] = __builtin_amdgcn_mfma_f32_16x16x32_bf16(qfh[kk], kl,
                                                            sv[ntl], 0, 0, 0);
          sv[ntl] = __builtin_amdgcn_mfma_f32_16x16x32_bf16(qfl[kk], kh,
                                                            sv[ntl], 0, 0, 0);
        }
      }
      // p = exp2(s*SC); per-lane l accumulation; split -> Ps (32-col half)
#pragma unroll
      for (int ntl = 0; ntl < 2; ntl++)
#pragma unroll
        for (int r = 0; r < 4; r++) {
          float p = __builtin_exp2f(sv[ntl][r] * SC);
          l_lane[r] += p;
          bf16 hh, ll;
          split2(p, hh, ll);
          Ps[w][0][qd * 4 + r][ntl * 16 + lm] = hh;
          Ps[w][1][qd * 4 + r][ntl * 16 + lm] = ll;
        }
      // PV for token half th (A k-local = qd*8 within the half)
      bf16x8 ph = *(const bf16x8*)&Ps[w][0][lm][qd * 8];
      bf16x8 pl = *(const bf16x8*)&Ps[w][1][lm][qd * 8];
#pragma unroll
      for (int nt = 0; nt < 4; nt++) {
        int drow = nt * 16 + lm;
        int slot = ((th * 4 + qd) ^ (lm & 7)) * 8;
        bf16x8 vh = *(const bf16x8*)&Vs[0][drow * 64 + slot];
        bf16x8 vl = *(const bf16x8*)&Vs[1][drow * 64 + slot];
        o[nt] = __builtin_amdgcn_mfma_f32_16x16x32_bf16(ph, vh, o[nt], 0, 0, 0);
        o[nt] = __builtin_amdgcn_mfma_f32_16x16x32_bf16(ph, vl, o[nt], 0, 0, 0);
        o[nt] = __builtin_amdgcn_mfma_f32_16x16x32_bf16(pl, vh, o[nt], 0, 0, 0);
      }
    }
  }
  // final l reduction across the 16 lanes of each quad-row
#pragma unroll
  for (int r = 0; r < 4; r++)
#pragma unroll
    for (int d = 8; d; d >>= 1) l_lane[r] += __shfl_xor(l_lane[r], d);
  // epilogue: reference's scrambled layout, pre-split
#pragma unroll
  for (int nt = 0; nt < 4; nt++)
#pragma unroll
    for (int r = 0; r < 4; r++) {
      int t = qt * 128 + w * 16 + qd * 4 + r;
      int d = nt * 16 + lm;
      int ttn = (t & 31) * 64 + d;
      int c = h * 64 + (t >> 5);
      float v = o[nt][r] / l_lane[r];
      bf16 hh, ll;
      split2(v, hh, ll);
      long idx = (bb + ttn) * (long)CE + c;
      attn_h[idx] = hh;
      attn_l[idx] = ll;
    }
#undef LOADT
}

// ------------------------------ Routing ------------------------------------
__global__ __launch_bounds__(64) void route_k(
    const float* __restrict__ hln, const float* __restrict__ noise,
    const float* __restrict__ wr, const float* __restrict__ br,
    const float* __restrict__ wn, const float* __restrict__ bn,
    int* __restrict__ top_e, float* __restrict__ gates,
    float* __restrict__ entb) {
  int n = blockIdx.x, lane = threadIdx.x;
  const float* hr = hln + (long)n * CE;
  float aR[NE], aN[NE];
#pragma unroll
  for (int e = 0; e < NE; e++) { aR[e] = 0.f; aN[e] = 0.f; }
  for (int i = lane; i < CE; i += 64) {
    float hv = hr[i];
#pragma unroll
    for (int e = 0; e < NE; e++) {
      aR[e] += hv * wr[i * NE + e];
      aN[e] += hv * wn[i * NE + e];
    }
  }
#pragma unroll
  for (int e = 0; e < NE; e++)
#pragma unroll
    for (int d = 32; d; d >>= 1) {
      aR[e] += __shfl_xor(aR[e], d);
      aN[e] += __shfl_xor(aN[e], d);
    }
  if (lane == 0) {
    float ns[NE];
#pragma unroll
    for (int e = 0; e < NE; e++) {
      float lg = aR[e] + br[e];
      float nl = aN[e] + bn[e];
      float sp = (nl > 20.f) ? nl : log1pf(expf(nl));
      ns[e] = lg + noise[(long)n * NE + e] * sp;
    }
    int i0 = 0;
#pragma unroll
    for (int e = 1; e < NE; e++)
      if (ns[e] > ns[i0]) i0 = e;
    int i1 = (i0 == 0) ? 1 : 0;
#pragma unroll
    for (int e = 0; e < NE; e++)
      if (e != i0 && ns[e] > ns[i1]) i1 = e;
    float v0 = ns[i0], v1 = ns[i1];
    float e1v = expf(v1 - v0);
    float inv2 = 1.f / (1.f + e1v);
    top_e[2 * n] = i0;
    top_e[2 * n + 1] = i1;
    gates[2 * n] = inv2;
    gates[2 * n + 1] = e1v * inv2;
    float ssum = 0.f, p[NE];
#pragma unroll
    for (int e = 0; e < NE; e++) {
      p[e] = expf(ns[e] - v0);
      ssum += p[e];
    }
    float is = 1.f / ssum, ent = 0.f;
#pragma unroll
    for (int e = 0; e < NE; e++) {
      float pe = p[e] * is;
      ent -= pe * logf(pe + 1e-8f);
    }
    entb[n] = ent;
  }
}

// ---------- capacity assignment: stable token-order compaction per expert ---
__global__ __launch_bounds__(256) void assign_k(const int* __restrict__ top_e,
                                                const float* __restrict__ gates,
                                                int* __restrict__ tokens,
                                                float* __restrict__ gslot,
                                                int* __restrict__ counts) {
  int e = blockIdx.x, tid = threadIdx.x, w = tid >> 6, lane = tid & 63;
  __shared__ int wtot[4];
  int basec = 0;
  for (int c = 0; c < 16; c++) {
    int n = c * 256 + tid;
    int e0 = top_e[2 * n], e1 = top_e[2 * n + 1];
    bool flag = (e0 == e) || (e1 == e);
    int rank = (e0 == e) ? 0 : 1;
    unsigned long long mask = __ballot(flag);
    int pre = __popcll(mask & ((1ull << lane) - 1ull));
    if (lane == 0) wtot[w] = __popcll(mask);
    __syncthreads();
    int wbase = basec;
    for (int i = 0; i < w; i++) wbase += wtot[i];
    if (flag) {
      int slot = wbase + pre;
      if (slot < CAP) {
        tokens[e * CAP + slot] = n;
        gslot[e * CAP + slot] = gates[2 * n + rank];
      }
    }
    int tot = wtot[0] + wtot[1] + wtot[2] + wtot[3];
    __syncthreads();
    basec += tot;
  }
  if (tid == 0) counts[e] = basec < CAP ? basec : CAP;
}

__global__ __launch_bounds__(256) void entropy_k(const float* __restrict__ entb,
                                                 float* __restrict__ outp) {
  int tid = threadIdx.x;
  float s = 0.f;
  for (int i = tid; i < NTOK; i += 256) s += entb[i];
#pragma unroll
  for (int d = 32; d; d >>= 1) s += __shfl_xor(s, d);
  __shared__ float rs[4];
  int w = tid >> 6, lane = tid & 63;
  if (lane == 0) rs[w] = s;
  __syncthreads();
  if (tid == 0)
    outp[(long)NTOK * CE] = (rs[0] + rs[1] + rs[2] + rs[3]) * (1.f / NTOK);
}

// ---------------------------------------------------------------------------
extern "C" void kernel_launch(void* const* d_in, const int* in_sizes, int n_in,
                              void* d_out, int out_size, void* d_ws,
                              size_t ws_size, hipStream_t stream) {
  const float* x = (const float*)d_in[0];
  const float* noise = (const float*)d_in[1];
  const float* gamma1 = (const float*)d_in[2];
  const float* beta1 = (const float*)d_in[3];
  const float* gamma2 = (const float*)d_in[4];
  const float* beta2 = (const float*)d_in[5];
  const float* w_qkv = (const float*)d_in[6];
  const float* w_out = (const float*)d_in[7];
  const float* w_route = (const float*)d_in[8];
  const float* b_route = (const float*)d_in[9];
  const float* w_noise = (const float*)d_in[10];
  const float* b_noise = (const float*)d_in[11];
  const float* w1 = (const float*)d_in[12];
  const float* b1 = (const float*)d_in[13];
  const float* w2 = (const float*)d_in[14];
  const float* b2 = (const float*)d_in[15];
  float* out = (float*)d_out;

  char* ws = (char*)d_ws;
  // Region A (67.1 MB): qkv/attn tensors, later reused as `hid`.
  size_t offA = 0;
  bf16* qkvh = (bf16*)(ws + offA);  offA += (size_t)NTOK * 2048 * 2;
  bf16* qkvl = (bf16*)(ws + offA);  offA += (size_t)NTOK * 2048 * 2;
  bf16* VTh = (bf16*)(ws + offA);   offA += (size_t)2 * 1024 * TT * 2;
  bf16* VTl = (bf16*)(ws + offA);   offA += (size_t)2 * 1024 * TT * 2;
  size_t attn_off = offA;
  bf16* attn_h = (bf16*)(ws + offA); offA += (size_t)NTOK * CE * 2;
  bf16* attn_l = (bf16*)(ws + offA); offA += (size_t)NTOK * CE * 2;
  bf16* hid = (bf16*)ws;                     // alias all of A
  float* vtmp = (float*)(ws + attn_off);     // alias attn_h+attn_l (16.8 MB)
  float* h2f = (float*)(ws + attn_off);      // alias (after attn consumed)
  size_t szA = offA;
  // Region B (33.6 MB): h1 + transposed small weights -> {h2h,h2l}.
  size_t offB = szA;
  bf16* h1h = (bf16*)(ws + offB);    offB += (size_t)NTOK * CE * 2;
  bf16* h1l = (bf16*)(ws + offB);    offB += (size_t)NTOK * CE * 2;
  bf16* wqkvTh = (bf16*)(ws + offB); offB += (size_t)3072 * 1024 * 2;
  bf16* wqkvTl = (bf16*)(ws + offB); offB += (size_t)3072 * 1024 * 2;
  bf16* woutTh = (bf16*)(ws + offB); offB += (size_t)1024 * 1024 * 2;
  bf16* woutTl = (bf16*)(ws + offB); offB += (size_t)1024 * 1024 * 2;
  bf16* h2h = (bf16*)(ws + szA);     // reuse h1 area after proj
  bf16* h2l = (bf16*)(ws + szA + (size_t)NTOK * CE * 2);
  // Region C (67.1 MB): w1T, later w2T.
  size_t offC = offB;
  bf16* w1T = (bf16*)(ws + offC);
  bf16* w2T = w1T;
  offC += (size_t)NE * DFF * CE * 2;
  // Small arrays.
  size_t offS = offC;
  int* top_e = (int*)(ws + offS);    offS += (size_t)NTOK * 2 * 4;
  float* gates = (float*)(ws + offS); offS += (size_t)NTOK * 2 * 4;
  int* toks = (int*)(ws + offS);     offS += (size_t)NE * CAP * 4;
  float* gslot = (float*)(ws + offS); offS += (size_t)NE * CAP * 4;
  int* counts = (int*)(ws + offS);   offS += 256;
  float* entb = (float*)(ws + offS); offS += (size_t)NTOK * 4;
  float* zp = (float*)(ws + offS);   offS += 256;  // zero page
  if (offS > ws_size) return;

  // 0) weight prep
  wsplit_k<true><<<dim3(48, 16, 1), 256, 0, stream>>>(w_qkv, wqkvTh, wqkvTl,
                                                      1024, 3072, 0, 0);
  wsplit_k<true><<<dim3(16, 16, 1), 256, 0, stream>>>(w_out, woutTh, woutTl,
                                                      1024, 1024, 0, 0);
  wsplit_k<false><<<dim3(64, 16, 8), 256, 0, stream>>>(
      w1, w1T, nullptr, 1024, DFF, (long)CE * DFF, (long)DFF * CE);
  // 1) LN1 (+ zero-page init)
  ln_k<<<NTOK, 256, 0, stream>>>(x, gamma1, beta1, nullptr, h1h, h1l, zp);
  // 2) qkv GEMM -> split Q/K + f32 V
  gemm_k<3, 0, false, 128><<<dim3(24, 32, 1), 256, 0, stream>>>(
      h1h, h1l, wqkvTh, wqkvTl, qkvh, qkvl, vtmp, NTOK, 3 * CE, CE, nullptr,
      nullptr, nullptr, nullptr, nullptr, 0, 0, 0, 0, (const bf16*)zp);
  // 3) V transpose+split
  vsplit_k<<<dim3(16, 32, 2), 256, 0, stream>>>(vtmp, VTh, VTl);
  // 4) flash attention (512 threads: 8 waves x 16 q-rows)
  attn_k<<<dim3(16, 16, 2), 512, 0, stream>>>(qkvh, qkvl, VTh, VTl, attn_h,
                                              attn_l);
  // 5) x2 = x + attn @ w_out -> d_out  (TM=64: 512 blocks)
  gemm_k<3, 1, false, 64><<<dim3(8, 64, 1), 256, 0, stream>>>(
      attn_h, attn_l, woutTh, woutTl, out, nullptr, nullptr, NTOK, CE, CE, x,
      nullptr, nullptr, nullptr, nullptr, 0, 0, 0, 0, (const bf16*)zp);
  // 6) LN2
  ln_k<<<NTOK, 256, 0, stream>>>(out, gamma2, beta2, h2f, h2h, h2l, nullptr);
  // 7) routing
  route_k<<<NTOK, 64, 0, stream>>>(h2f, noise, w_route, b_route, w_noise,
                                   b_noise, top_e, gates, entb);
  // 8) capacity-limited stable assignment (+ per-slot gates)
  assign_k<<<NE, 256, 0, stream>>>(top_e, gates, toks, gslot, counts);
  // 9) expert GEMM1: hid = relu(gather(h2) @ w1[e] + b1[e])
  gemm_k<1, 2, true, 128><<<dim3(DFF / 128, CAP / 128, NE), 256, 0, stream>>>(
      h2h, nullptr, w1T, nullptr, hid, nullptr, nullptr, CAP, DFF, CE, nullptr,
      b1, toks, counts, nullptr, 0, (long)DFF * CE, (long)CAP * DFF, DFF,
      (const bf16*)zp);
  // 10) convert w2 into the (now free) w1T buffer
  wsplit_k<false><<<dim3(16, 64, 8), 256, 0, stream>>>(
      w2, w2T, nullptr, DFF, CE, (long)DFF * CE, (long)CE * DFF);
  // 11) expert GEMM2 fused with gather: out[tok] += g*(hid@w2[e] + b2[e])
  gemm_k<1, 3, false, 128><<<dim3(CE / 128, CAP / 128, NE), 256, 0, stream>>>(
      hid, nullptr, w2T, nullptr, out, nullptr, nullptr, CAP, CE, DFF, nullptr,
      b2, toks, counts, gslot, (long)CAP * DFF, (long)CE * DFF, 0, CE,
      (const bf16*)zp);
  // 12) entropy mean
  entropy_k<<<1, 256, 0, stream>>>(entb, out);
}